// Round 1
// baseline (1020.201 us; speedup 1.0000x reference)
//
#include <hip/hip_runtime.h>
#include <cstddef>

// RetNetAttention: x(2,4096,1024) fp32; W_qkv(3072,1024); W_o(1024,1024); log_gamma(16)
// Chunkwise linear-attention decomposition, chunk=64, all fp32 (round 1 baseline).

#define NB 2
#define NL 4096
#define ND 1024
#define NH 16
#define DKH 64
#define CK 64              // chunk length
#define NCH (NL / CK)      // 64 chunks
#define NM (NB * NL)       // 8192 rows

__device__ __forceinline__ float dsigmoid(float x) { return 1.0f / (1.0f + __expf(-x)); }

// ================= GEMM: C[m,n] = sum_k A[m,k] * Bmat[n,k]  (A@B^T, NT) ============
// 128x128 tile, BK=16, 256 threads, 8x8 per thread, LDS-transposed tiles.

__global__ __launch_bounds__(256)
void k_qkv_gemm(const float* __restrict__ A, const float* __restrict__ Bmat,
                float* __restrict__ Qb, float* __restrict__ Kb, float* __restrict__ Vb)
{
    __shared__ float As[16][128];
    __shared__ float Bs[16][128];
    const int tid = threadIdx.x;
    const int tx = tid & 15;
    const int ty = tid >> 4;
    const int row0 = blockIdx.y * 128;
    const int col0 = blockIdx.x * 128;
    float acc[8][8];
#pragma unroll
    for (int i = 0; i < 8; ++i)
#pragma unroll
        for (int j = 0; j < 8; ++j) acc[i][j] = 0.0f;

    for (int k0 = 0; k0 < ND; k0 += 16) {
#pragma unroll
        for (int it = 0; it < 2; ++it) {
            int f4 = tid + it * 256;          // 0..511
            int r  = f4 >> 2;                 // 0..127
            int c4 = (f4 & 3) << 2;           // 0,4,8,12
            float4 a = *(const float4*)(A + (size_t)(row0 + r) * ND + k0 + c4);
            As[c4 + 0][r] = a.x; As[c4 + 1][r] = a.y; As[c4 + 2][r] = a.z; As[c4 + 3][r] = a.w;
            float4 b = *(const float4*)(Bmat + (size_t)(col0 + r) * ND + k0 + c4);
            Bs[c4 + 0][r] = b.x; Bs[c4 + 1][r] = b.y; Bs[c4 + 2][r] = b.z; Bs[c4 + 3][r] = b.w;
        }
        __syncthreads();
#pragma unroll
        for (int kk = 0; kk < 16; ++kk) {
            float ar[8], br[8];
            *(float4*)(ar + 0) = *(const float4*)(&As[kk][ty * 8 + 0]);
            *(float4*)(ar + 4) = *(const float4*)(&As[kk][ty * 8 + 4]);
            *(float4*)(br + 0) = *(const float4*)(&Bs[kk][tx * 8 + 0]);
            *(float4*)(br + 4) = *(const float4*)(&Bs[kk][tx * 8 + 4]);
#pragma unroll
            for (int i = 0; i < 8; ++i)
#pragma unroll
                for (int j = 0; j < 8; ++j) acc[i][j] += ar[i] * br[j];
        }
        __syncthreads();
    }

    // scatter epilogue: col -> (three, h, d); store as (B,H,L,dk)
    const int colb  = col0 + tx * 8;
    const int three = colb >> 10;
    const int hh    = (colb >> 6) & (NH - 1);
    const int d0    = colb & (DKH - 1);     // 8-aligned, never crosses head boundary
    float* dst = (three == 0) ? Qb : ((three == 1) ? Kb : Vb);
#pragma unroll
    for (int i = 0; i < 8; ++i) {
        int m = row0 + ty * 8 + i;
        int b = m >> 12;                    // NL = 4096
        int t = m & (NL - 1);
        float* p = dst + ((((size_t)b * NH + hh) * NL + t) * DKH + d0);
        *(float4*)(p + 0) = make_float4(acc[i][0], acc[i][1], acc[i][2], acc[i][3]);
        *(float4*)(p + 4) = make_float4(acc[i][4], acc[i][5], acc[i][6], acc[i][7]);
    }
}

__global__ __launch_bounds__(256)
void k_out_gemm(const float* __restrict__ A, const float* __restrict__ Bmat,
                float* __restrict__ C)
{
    __shared__ float As[16][128];
    __shared__ float Bs[16][128];
    const int tid = threadIdx.x;
    const int tx = tid & 15;
    const int ty = tid >> 4;
    const int row0 = blockIdx.y * 128;
    const int col0 = blockIdx.x * 128;
    float acc[8][8];
#pragma unroll
    for (int i = 0; i < 8; ++i)
#pragma unroll
        for (int j = 0; j < 8; ++j) acc[i][j] = 0.0f;

    for (int k0 = 0; k0 < ND; k0 += 16) {
#pragma unroll
        for (int it = 0; it < 2; ++it) {
            int f4 = tid + it * 256;
            int r  = f4 >> 2;
            int c4 = (f4 & 3) << 2;
            float4 a = *(const float4*)(A + (size_t)(row0 + r) * ND + k0 + c4);
            As[c4 + 0][r] = a.x; As[c4 + 1][r] = a.y; As[c4 + 2][r] = a.z; As[c4 + 3][r] = a.w;
            float4 b = *(const float4*)(Bmat + (size_t)(col0 + r) * ND + k0 + c4);
            Bs[c4 + 0][r] = b.x; Bs[c4 + 1][r] = b.y; Bs[c4 + 2][r] = b.z; Bs[c4 + 3][r] = b.w;
        }
        __syncthreads();
#pragma unroll
        for (int kk = 0; kk < 16; ++kk) {
            float ar[8], br[8];
            *(float4*)(ar + 0) = *(const float4*)(&As[kk][ty * 8 + 0]);
            *(float4*)(ar + 4) = *(const float4*)(&As[kk][ty * 8 + 4]);
            *(float4*)(br + 0) = *(const float4*)(&Bs[kk][tx * 8 + 0]);
            *(float4*)(br + 4) = *(const float4*)(&Bs[kk][tx * 8 + 4]);
#pragma unroll
            for (int i = 0; i < 8; ++i)
#pragma unroll
                for (int j = 0; j < 8; ++j) acc[i][j] += ar[i] * br[j];
        }
        __syncthreads();
    }
#pragma unroll
    for (int i = 0; i < 8; ++i) {
        int m = row0 + ty * 8 + i;
        float* p = C + (size_t)m * ND + col0 + tx * 8;
        *(float4*)(p + 0) = make_float4(acc[i][0], acc[i][1], acc[i][2], acc[i][3]);
        *(float4*)(p + 4) = make_float4(acc[i][4], acc[i][5], acc[i][6], acc[i][7]);
    }
}

// ================= LayerNorm over dk=64 for K rows (one wave per row) =================
__global__ __launch_bounds__(256)
void k_ln(float* __restrict__ Kb)
{
    int row  = blockIdx.x * 4 + (threadIdx.x >> 6);
    int lane = threadIdx.x & 63;
    float* p = Kb + (size_t)row * DKH + lane;
    float x = *p;
    float s = x;
#pragma unroll
    for (int o = 32; o > 0; o >>= 1) s += __shfl_xor(s, o);
    float mu = s * (1.0f / 64.0f);
    float dv = x - mu;
    float q = dv * dv;
#pragma unroll
    for (int o = 32; o > 0; o >>= 1) q += __shfl_xor(q, o);
    float rstd = rsqrtf(q * (1.0f / 64.0f) + 1e-5f);
    *p = dv * rstd;
}

// ============ per-chunk local state: SL[d][e] = sum_s gamma^{C-1-s} v_s[d] k_s[e] ============
__global__ __launch_bounds__(256)
void k_chunk_state(const float* __restrict__ Kb, const float* __restrict__ Vb,
                   const float* __restrict__ lg, float* __restrict__ SL)
{
    __shared__ float Ks[CK][DKH];
    __shared__ float Vw[CK][DKH];
    const int blk = blockIdx.x;
    const int c   = blk & (NCH - 1);
    const int bh  = blk >> 6;                // NCH = 64
    const int h   = bh & (NH - 1);
    const float gamma = dsigmoid(lg[h]);
    const int tid = threadIdx.x;
    const float* Kc = Kb + ((size_t)bh * NL + c * CK) * DKH;
    const float* Vc = Vb + ((size_t)bh * NL + c * CK) * DKH;
#pragma unroll
    for (int it = 0; it < 4; ++it) {
        int f4 = tid + it * 256;             // 0..1023
        int r  = f4 >> 4;                    // 0..63  (s index)
        int c4 = (f4 & 15) << 2;
        *(float4*)&Ks[r][c4] = *(const float4*)(Kc + (size_t)r * DKH + c4);
        float4 v = *(const float4*)(Vc + (size_t)r * DKH + c4);
        float w = __powf(gamma, (float)(CK - 1 - r));
        v.x *= w; v.y *= w; v.z *= w; v.w *= w;
        *(float4*)&Vw[r][c4] = v;
    }
    __syncthreads();
    const int e0 = (tid & 15) << 2;
    const int d0 = (tid >> 4) << 2;
    float acc[4][4];
#pragma unroll
    for (int i = 0; i < 4; ++i)
#pragma unroll
        for (int j = 0; j < 4; ++j) acc[i][j] = 0.0f;
    for (int s = 0; s < CK; ++s) {
        float vv[4], kk[4];
        *(float4*)vv = *(const float4*)&Vw[s][d0];
        *(float4*)kk = *(const float4*)&Ks[s][e0];
#pragma unroll
        for (int i = 0; i < 4; ++i)
#pragma unroll
            for (int j = 0; j < 4; ++j) acc[i][j] += vv[i] * kk[j];
    }
    float* out = SL + (size_t)blk * (DKH * DKH);
#pragma unroll
    for (int i = 0; i < 4; ++i)
        *(float4*)(out + (d0 + i) * DKH + e0) =
            make_float4(acc[i][0], acc[i][1], acc[i][2], acc[i][3]);
}

// ============ sequential scan over chunks (in place: SL[c] -> S_start[c]) ============
__global__ __launch_bounds__(256)
void k_scan(float* __restrict__ SLSS, const float* __restrict__ lg)
{
    const int bh = blockIdx.x;
    const int h  = bh & (NH - 1);
    const float gamma = dsigmoid(lg[h]);
    const float dc = __powf(gamma, (float)CK);
    const int tid = threadIdx.x;
    float* base = SLSS + (size_t)bh * NCH * (DKH * DKH) + (size_t)tid * 16;
    float4 s0 = make_float4(0,0,0,0), s1 = s0, s2 = s0, s3 = s0;
    for (int c = 0; c < NCH; ++c) {
        float4* p = (float4*)(base + (size_t)c * (DKH * DKH));
        float4 l0 = p[0], l1 = p[1], l2 = p[2], l3 = p[3];
        p[0] = s0; p[1] = s1; p[2] = s2; p[3] = s3;   // state BEFORE chunk c
        s0.x = s0.x * dc + l0.x; s0.y = s0.y * dc + l0.y; s0.z = s0.z * dc + l0.z; s0.w = s0.w * dc + l0.w;
        s1.x = s1.x * dc + l1.x; s1.y = s1.y * dc + l1.y; s1.z = s1.z * dc + l1.z; s1.w = s1.w * dc + l1.w;
        s2.x = s2.x * dc + l2.x; s2.y = s2.y * dc + l2.y; s2.z = s2.z * dc + l2.z; s2.w = s2.w * dc + l2.w;
        s3.x = s3.x * dc + l3.x; s3.y = s3.y * dc + l3.y; s3.z = s3.z * dc + l3.z; s3.w = s3.w * dc + l3.w;
    }
}

// ============ per-chunk output: Y = decaymask(QK^T) V + gamma^{t+1} (S_start q) ============
__global__ __launch_bounds__(256)
void k_chunk_out(const float* __restrict__ Qb, const float* __restrict__ Kb,
                 const float* __restrict__ Vb, const float* __restrict__ SS,
                 const float* __restrict__ lg, float* __restrict__ Y)
{
    __shared__ float Qs[CK][DKH];     // Q rows
    __shared__ float bufKV[DKH][CK];  // phase A: K^T (KT[k][s]); phase B: V row-major [s][d]
    __shared__ float Ps[CK][CK];      // decayed scores
    __shared__ float Sst[DKH][DKH];   // S_start transposed: Sst[e][d]
    const int blk = blockIdx.x;
    const int c   = blk & (NCH - 1);
    const int bh  = blk >> 6;
    const int h   = bh & (NH - 1);
    const int b   = bh >> 4;
    const float gamma = dsigmoid(lg[h]);
    const int tid = threadIdx.x;
    const float* Qc = Qb + ((size_t)bh * NL + c * CK) * DKH;
    const float* Kc = Kb + ((size_t)bh * NL + c * CK) * DKH;
    const float* Vc = Vb + ((size_t)bh * NL + c * CK) * DKH;
    const float* Sc = SS + (size_t)blk * (DKH * DKH);

    // load Q (row-major), K (transposed), S_start (transposed)
#pragma unroll
    for (int it = 0; it < 4; ++it) {
        int f4 = tid + it * 256;
        int r  = f4 >> 4;
        int c4 = (f4 & 15) << 2;
        *(float4*)&Qs[r][c4] = *(const float4*)(Qc + (size_t)r * DKH + c4);
        float4 kv = *(const float4*)(Kc + (size_t)r * DKH + c4);
        bufKV[c4 + 0][r] = kv.x; bufKV[c4 + 1][r] = kv.y;
        bufKV[c4 + 2][r] = kv.z; bufKV[c4 + 3][r] = kv.w;
        float4 sv = *(const float4*)(Sc + (size_t)r * DKH + c4);
        Sst[c4 + 0][r] = sv.x; Sst[c4 + 1][r] = sv.y;
        Sst[c4 + 2][r] = sv.z; Sst[c4 + 3][r] = sv.w;
    }
    __syncthreads();

    // phase A: P[t][s] = gamma^{t-s} (q_t . k_s) for s<=t else 0
    const int tt0 = (tid >> 4) << 2;
    const int ss0 = (tid & 15) << 2;
    {
        float pa[4][4];
#pragma unroll
        for (int i = 0; i < 4; ++i)
#pragma unroll
            for (int j = 0; j < 4; ++j) pa[i][j] = 0.0f;
        for (int kk = 0; kk < DKH; ++kk) {
            float qa[4], ka[4];
#pragma unroll
            for (int i = 0; i < 4; ++i) qa[i] = Qs[tt0 + i][kk];
            *(float4*)ka = *(const float4*)&bufKV[kk][ss0];
#pragma unroll
            for (int i = 0; i < 4; ++i)
#pragma unroll
                for (int j = 0; j < 4; ++j) pa[i][j] += qa[i] * ka[j];
        }
#pragma unroll
        for (int i = 0; i < 4; ++i)
#pragma unroll
            for (int j = 0; j < 4; ++j) {
                int dt = (tt0 + i) - (ss0 + j);
                Ps[tt0 + i][ss0 + j] = (dt >= 0) ? pa[i][j] * __powf(gamma, (float)dt) : 0.0f;
            }
    }
    __syncthreads();

    // reload bufKV with V (row-major)
#pragma unroll
    for (int it = 0; it < 4; ++it) {
        int f4 = tid + it * 256;
        int r  = f4 >> 4;
        int c4 = (f4 & 15) << 2;
        *(float4*)&((float(*)[DKH])bufKV)[r][c4] = *(const float4*)(Vc + (size_t)r * DKH + c4);
    }
    __syncthreads();

    // phase B: Y[t][d] = sum_s P[t][s] V[s][d] + gamma^{t+1} sum_e Sst[e][d] Q[t][e]
    const int t0  = tt0;
    const int dd0 = ss0;
    float ya[4][4], yb[4][4];
#pragma unroll
    for (int i = 0; i < 4; ++i)
#pragma unroll
        for (int j = 0; j < 4; ++j) { ya[i][j] = 0.0f; yb[i][j] = 0.0f; }
    const float (*Vs)[DKH] = (const float(*)[DKH])bufKV;
    for (int s = 0; s < CK; ++s) {
        float pr[4], vr[4];
#pragma unroll
        for (int i = 0; i < 4; ++i) pr[i] = Ps[t0 + i][s];
        *(float4*)vr = *(const float4*)&Vs[s][dd0];
#pragma unroll
        for (int i = 0; i < 4; ++i)
#pragma unroll
            for (int j = 0; j < 4; ++j) ya[i][j] += pr[i] * vr[j];
    }
    for (int e = 0; e < DKH; ++e) {
        float qr[4], sr[4];
#pragma unroll
        for (int i = 0; i < 4; ++i) qr[i] = Qs[t0 + i][e];
        *(float4*)sr = *(const float4*)&Sst[e][dd0];
#pragma unroll
        for (int i = 0; i < 4; ++i)
#pragma unroll
            for (int j = 0; j < 4; ++j) yb[i][j] += qr[i] * sr[j];
    }
#pragma unroll
    for (int i = 0; i < 4; ++i) {
        float g = __powf(gamma, (float)(t0 + i + 1));
        int tglob = c * CK + t0 + i;
        float* p = Y + ((size_t)(b * NL + tglob) * ND) + h * DKH + dd0;
        *(float4*)p = make_float4(ya[i][0] + g * yb[i][0], ya[i][1] + g * yb[i][1],
                                  ya[i][2] + g * yb[i][2], ya[i][3] + g * yb[i][3]);
    }
}

extern "C" void kernel_launch(void* const* d_in, const int* in_sizes, int n_in,
                              void* d_out, int out_size, void* d_ws, size_t ws_size,
                              hipStream_t stream)
{
    (void)in_sizes; (void)n_in; (void)out_size; (void)ws_size;
    const float* x  = (const float*)d_in[0];
    const float* Wq = (const float*)d_in[1];
    const float* Wo = (const float*)d_in[2];
    const float* lg = (const float*)d_in[3];
    float* out = (float*)d_out;

    const size_t SZ = (size_t)NB * NH * NL * DKH;   // 8M floats = 32 MB
    float* Qb = (float*)d_ws;
    float* Kb = Qb + SZ;
    float* Vb = Kb + SZ;
    float* SL = Vb + SZ;                            // also holds S_start after k_scan
    float* Yb = SL + (size_t)NB * NH * NCH * DKH * DKH;

    k_qkv_gemm<<<dim3(3 * ND / 128, NM / 128), 256, 0, stream>>>(x, Wq, Qb, Kb, Vb);
    k_ln<<<dim3(NB * NH * NL / 4), 256, 0, stream>>>(Kb);
    k_chunk_state<<<dim3(NB * NH * NCH), 256, 0, stream>>>(Kb, Vb, lg, SL);
    k_scan<<<dim3(NB * NH), 256, 0, stream>>>(SL, lg);
    k_chunk_out<<<dim3(NB * NH * NCH), 256, 0, stream>>>(Qb, Kb, Vb, SL, lg, Yb);
    k_out_gemm<<<dim3(ND / 128, NM / 128), 256, 0, stream>>>(Yb, Wo, out);
}

// Round 2
// 284.361 us; speedup vs baseline: 3.5877x; 3.5877x over previous
//
#include <hip/hip_runtime.h>
#include <cstddef>

// RetNetAttention: x(2,4096,1024) fp32; W_qkv(3072,1024); W_o(1024,1024); log_gamma(16)
// Round 2: bf16-MFMA GEMMs (m97 128x128 structure, global_load_lds w=16),
// chunkwise linear attention in fp32, Yb emitted bf16, scan occupancy fix.

#define NB 2
#define NL 4096
#define ND 1024
#define NH 16
#define DKH 64
#define CK 64              // chunk length
#define NCH (NL / CK)      // 64 chunks
#define NM (NB * NL)       // 8192 rows
#define KD 1024            // GEMM K

typedef __attribute__((ext_vector_type(8))) short bf16x8;
typedef __attribute__((ext_vector_type(4))) float f32x4;

__device__ __forceinline__ float dsigmoid(float x) { return 1.0f / (1.0f + __expf(-x)); }

__device__ __forceinline__ unsigned short f2bf(float f) {
    unsigned u = __float_as_uint(f);
    u = (u + 0x7fffu + ((u >> 16) & 1u)) >> 16;
    return (unsigned short)u;
}

__device__ __forceinline__ void gload16(const void* g, void* l) {
    __builtin_amdgcn_global_load_lds(
        (const __attribute__((address_space(1))) unsigned int*)g,
        (__attribute__((address_space(3))) unsigned int*)l, 16, 0, 0);
}

// ================= fp32 -> bf16 cast (vectorized) =================
__global__ __launch_bounds__(256)
void k_cast_bf16(const float* __restrict__ in, unsigned short* __restrict__ out, int n4)
{
    int i = blockIdx.x * 256 + threadIdx.x;
    int stride = gridDim.x * 256;
    for (; i < n4; i += stride) {
        float4 v = ((const float4*)in)[i];
        ushort4 o;
        o.x = f2bf(v.x); o.y = f2bf(v.y); o.z = f2bf(v.z); o.w = f2bf(v.w);
        ((ushort4*)out)[i] = o;
    }
}

// ====== bf16 MFMA GEMM (NT): C[m,n] = sum_k A[m,k]*Bm[n,k], M rows x 128 cols/block ======
// 128x128 tile, BK=32, 256 thr (4 waves, 2x2), 4x4 16x16x32 frags/wave.
// QKV variant scatters into (B,H,L,dk) Q/K/V fp32 buffers.

__global__ __launch_bounds__(256)
void k_gemm_qkv_bf16(const unsigned short* __restrict__ A, const unsigned short* __restrict__ Bm,
                     float* __restrict__ Qb, float* __restrict__ Kb, float* __restrict__ Vb)
{
    __shared__ short As[128 * 32];
    __shared__ short Bs[128 * 32];
    const int tid = threadIdx.x;
    const int w = tid >> 6, lane = tid & 63;
    const int wr = w >> 1, wc = w & 1;
    const int lr = lane & 15, lk = lane >> 4;
    const int row0 = blockIdx.y * 128, col0 = blockIdx.x * 128;

    const unsigned short* gA = A + (size_t)(row0 + (tid >> 2)) * KD + (tid & 3) * 8;
    const unsigned short* gB = Bm + (size_t)(col0 + (tid >> 2)) * KD + (tid & 3) * 8;
    short* lA0 = As + w * 512;
    short* lA1 = As + 2048 + w * 512;
    short* lB0 = Bs + w * 512;
    short* lB1 = Bs + 2048 + w * 512;

    f32x4 acc[4][4];
#pragma unroll
    for (int m = 0; m < 4; ++m)
#pragma unroll
        for (int n = 0; n < 4; ++n) acc[m][n] = (f32x4){0.f, 0.f, 0.f, 0.f};

    const int aoff = (wr * 64 + lr) * 32 + lk * 8;
    const int boff = (wc * 64 + lr) * 32 + lk * 8;

    for (int k0 = 0; k0 < KD; k0 += 32) {
        gload16(gA + k0, lA0);
        gload16(gA + (size_t)64 * KD + k0, lA1);
        gload16(gB + k0, lB0);
        gload16(gB + (size_t)64 * KD + k0, lB1);
        __syncthreads();
        bf16x8 a[4], b[4];
#pragma unroll
        for (int m = 0; m < 4; ++m) a[m] = *(const bf16x8*)(As + aoff + m * 512);
#pragma unroll
        for (int n = 0; n < 4; ++n) b[n] = *(const bf16x8*)(Bs + boff + n * 512);
#pragma unroll
        for (int m = 0; m < 4; ++m)
#pragma unroll
            for (int n = 0; n < 4; ++n)
                acc[m][n] = __builtin_amdgcn_mfma_f32_16x16x32_bf16(a[m], b[n], acc[m][n], 0, 0, 0);
        __syncthreads();
    }

    // epilogue: C row = row0+wr*64+m*16+lk*4+j ; col = col0+wc*64+n*16+lr
#pragma unroll
    for (int m = 0; m < 4; ++m) {
        const int mrow0 = row0 + wr * 64 + m * 16 + lk * 4;
#pragma unroll
        for (int n = 0; n < 4; ++n) {
            const int gcol = col0 + wc * 64 + n * 16 + lr;
            const int three = gcol >> 10;
            const int h = (gcol >> 6) & (NH - 1);
            const int d = gcol & (DKH - 1);
            float* dst = (three == 0) ? Qb : ((three == 1) ? Kb : Vb);
#pragma unroll
            for (int j = 0; j < 4; ++j) {
                const int mr = mrow0 + j;
                const int b = mr >> 12;
                const int t = mr & (NL - 1);
                dst[(((size_t)b * NH + h) * NL + t) * DKH + d] = acc[m][n][j];
            }
        }
    }
}

__global__ __launch_bounds__(256)
void k_gemm_out_bf16(const unsigned short* __restrict__ A, const unsigned short* __restrict__ Bm,
                     float* __restrict__ C)
{
    __shared__ short As[128 * 32];
    __shared__ short Bs[128 * 32];
    const int tid = threadIdx.x;
    const int w = tid >> 6, lane = tid & 63;
    const int wr = w >> 1, wc = w & 1;
    const int lr = lane & 15, lk = lane >> 4;
    const int row0 = blockIdx.y * 128, col0 = blockIdx.x * 128;

    const unsigned short* gA = A + (size_t)(row0 + (tid >> 2)) * KD + (tid & 3) * 8;
    const unsigned short* gB = Bm + (size_t)(col0 + (tid >> 2)) * KD + (tid & 3) * 8;
    short* lA0 = As + w * 512;
    short* lA1 = As + 2048 + w * 512;
    short* lB0 = Bs + w * 512;
    short* lB1 = Bs + 2048 + w * 512;

    f32x4 acc[4][4];
#pragma unroll
    for (int m = 0; m < 4; ++m)
#pragma unroll
        for (int n = 0; n < 4; ++n) acc[m][n] = (f32x4){0.f, 0.f, 0.f, 0.f};

    const int aoff = (wr * 64 + lr) * 32 + lk * 8;
    const int boff = (wc * 64 + lr) * 32 + lk * 8;

    for (int k0 = 0; k0 < KD; k0 += 32) {
        gload16(gA + k0, lA0);
        gload16(gA + (size_t)64 * KD + k0, lA1);
        gload16(gB + k0, lB0);
        gload16(gB + (size_t)64 * KD + k0, lB1);
        __syncthreads();
        bf16x8 a[4], b[4];
#pragma unroll
        for (int m = 0; m < 4; ++m) a[m] = *(const bf16x8*)(As + aoff + m * 512);
#pragma unroll
        for (int n = 0; n < 4; ++n) b[n] = *(const bf16x8*)(Bs + boff + n * 512);
#pragma unroll
        for (int m = 0; m < 4; ++m)
#pragma unroll
            for (int n = 0; n < 4; ++n)
                acc[m][n] = __builtin_amdgcn_mfma_f32_16x16x32_bf16(a[m], b[n], acc[m][n], 0, 0, 0);
        __syncthreads();
    }

#pragma unroll
    for (int m = 0; m < 4; ++m) {
        const int mrow0 = row0 + wr * 64 + m * 16 + lk * 4;
#pragma unroll
        for (int n = 0; n < 4; ++n) {
            const int gcol = col0 + wc * 64 + n * 16 + lr;
#pragma unroll
            for (int j = 0; j < 4; ++j)
                C[(size_t)(mrow0 + j) * ND + gcol] = acc[m][n][j];
        }
    }
}

// ================= LayerNorm over dk=64 for K rows (one wave per row) =================
__global__ __launch_bounds__(256)
void k_ln(float* __restrict__ Kb)
{
    int row  = blockIdx.x * 4 + (threadIdx.x >> 6);
    int lane = threadIdx.x & 63;
    float* p = Kb + (size_t)row * DKH + lane;
    float x = *p;
    float s = x;
#pragma unroll
    for (int o = 32; o > 0; o >>= 1) s += __shfl_xor(s, o);
    float mu = s * (1.0f / 64.0f);
    float dv = x - mu;
    float q = dv * dv;
#pragma unroll
    for (int o = 32; o > 0; o >>= 1) q += __shfl_xor(q, o);
    float rstd = rsqrtf(q * (1.0f / 64.0f) + 1e-5f);
    *p = dv * rstd;
}

// ============ per-chunk local state: SL[d][e] = sum_s gamma^{C-1-s} v_s[d] k_s[e] ============
__global__ __launch_bounds__(256)
void k_chunk_state(const float* __restrict__ Kb, const float* __restrict__ Vb,
                   const float* __restrict__ lg, float* __restrict__ SL)
{
    __shared__ float Ks[CK][DKH];
    __shared__ float Vw[CK][DKH];
    const int blk = blockIdx.x;
    const int c   = blk & (NCH - 1);
    const int bh  = blk >> 6;
    const int h   = bh & (NH - 1);
    const float gamma = dsigmoid(lg[h]);
    const int tid = threadIdx.x;
    const float* Kc = Kb + ((size_t)bh * NL + c * CK) * DKH;
    const float* Vc = Vb + ((size_t)bh * NL + c * CK) * DKH;
#pragma unroll
    for (int it = 0; it < 4; ++it) {
        int f4 = tid + it * 256;
        int r  = f4 >> 4;
        int c4 = (f4 & 15) << 2;
        *(float4*)&Ks[r][c4] = *(const float4*)(Kc + (size_t)r * DKH + c4);
        float4 v = *(const float4*)(Vc + (size_t)r * DKH + c4);
        float w = __powf(gamma, (float)(CK - 1 - r));
        v.x *= w; v.y *= w; v.z *= w; v.w *= w;
        *(float4*)&Vw[r][c4] = v;
    }
    __syncthreads();
    const int e0 = (tid & 15) << 2;
    const int d0 = (tid >> 4) << 2;
    float acc[4][4];
#pragma unroll
    for (int i = 0; i < 4; ++i)
#pragma unroll
        for (int j = 0; j < 4; ++j) acc[i][j] = 0.0f;
    for (int s = 0; s < CK; ++s) {
        float vv[4], kk[4];
        *(float4*)vv = *(const float4*)&Vw[s][d0];
        *(float4*)kk = *(const float4*)&Ks[s][e0];
#pragma unroll
        for (int i = 0; i < 4; ++i)
#pragma unroll
            for (int j = 0; j < 4; ++j) acc[i][j] += vv[i] * kk[j];
    }
    float* out = SL + (size_t)blk * (DKH * DKH);
#pragma unroll
    for (int i = 0; i < 4; ++i)
        *(float4*)(out + (d0 + i) * DKH + e0) =
            make_float4(acc[i][0], acc[i][1], acc[i][2], acc[i][3]);
}

// ============ sequential scan over chunks (in place), quarter-state per block ============
__global__ __launch_bounds__(256)
void k_scan(float* __restrict__ SLSS, const float* __restrict__ lg)
{
    const int bh = blockIdx.x;
    const int qt = blockIdx.y;
    const int h  = bh & (NH - 1);
    const float gamma = dsigmoid(lg[h]);
    const float dc = __powf(gamma, (float)CK);
    float* base = SLSS + (size_t)bh * NCH * (DKH * DKH) + qt * 1024 + threadIdx.x * 4;
    float4 s = make_float4(0, 0, 0, 0);
    for (int c = 0; c < NCH; ++c) {
        float4* p = (float4*)(base + (size_t)c * (DKH * DKH));
        float4 l = *p;
        *p = s;
        s.x = s.x * dc + l.x; s.y = s.y * dc + l.y;
        s.z = s.z * dc + l.z; s.w = s.w * dc + l.w;
    }
}

// ============ per-chunk output: Y = decaymask(QK^T) V + gamma^{t+1} (S_start q), bf16 out ============
__global__ __launch_bounds__(256)
void k_chunk_out(const float* __restrict__ Qb, const float* __restrict__ Kb,
                 const float* __restrict__ Vb, const float* __restrict__ SS,
                 const float* __restrict__ lg, unsigned short* __restrict__ Y)
{
    __shared__ float Qs[CK][DKH];
    __shared__ float bufKV[DKH][CK];
    __shared__ float Ps[CK][CK];
    __shared__ float Sst[DKH][DKH];
    const int blk = blockIdx.x;
    const int c   = blk & (NCH - 1);
    const int bh  = blk >> 6;
    const int h   = bh & (NH - 1);
    const int b   = bh >> 4;
    const float gamma = dsigmoid(lg[h]);
    const int tid = threadIdx.x;
    const float* Qc = Qb + ((size_t)bh * NL + c * CK) * DKH;
    const float* Kc = Kb + ((size_t)bh * NL + c * CK) * DKH;
    const float* Vc = Vb + ((size_t)bh * NL + c * CK) * DKH;
    const float* Sc = SS + (size_t)blk * (DKH * DKH);

#pragma unroll
    for (int it = 0; it < 4; ++it) {
        int f4 = tid + it * 256;
        int r  = f4 >> 4;
        int c4 = (f4 & 15) << 2;
        *(float4*)&Qs[r][c4] = *(const float4*)(Qc + (size_t)r * DKH + c4);
        float4 kv = *(const float4*)(Kc + (size_t)r * DKH + c4);
        bufKV[c4 + 0][r] = kv.x; bufKV[c4 + 1][r] = kv.y;
        bufKV[c4 + 2][r] = kv.z; bufKV[c4 + 3][r] = kv.w;
        float4 sv = *(const float4*)(Sc + (size_t)r * DKH + c4);
        Sst[c4 + 0][r] = sv.x; Sst[c4 + 1][r] = sv.y;
        Sst[c4 + 2][r] = sv.z; Sst[c4 + 3][r] = sv.w;
    }
    __syncthreads();

    const int tt0 = (tid >> 4) << 2;
    const int ss0 = (tid & 15) << 2;
    {
        float pa[4][4];
#pragma unroll
        for (int i = 0; i < 4; ++i)
#pragma unroll
            for (int j = 0; j < 4; ++j) pa[i][j] = 0.0f;
        for (int kk = 0; kk < DKH; ++kk) {
            float qa[4], ka[4];
#pragma unroll
            for (int i = 0; i < 4; ++i) qa[i] = Qs[tt0 + i][kk];
            *(float4*)ka = *(const float4*)&bufKV[kk][ss0];
#pragma unroll
            for (int i = 0; i < 4; ++i)
#pragma unroll
                for (int j = 0; j < 4; ++j) pa[i][j] += qa[i] * ka[j];
        }
#pragma unroll
        for (int i = 0; i < 4; ++i)
#pragma unroll
            for (int j = 0; j < 4; ++j) {
                int dt = (tt0 + i) - (ss0 + j);
                Ps[tt0 + i][ss0 + j] = (dt >= 0) ? pa[i][j] * __powf(gamma, (float)dt) : 0.0f;
            }
    }
    __syncthreads();

#pragma unroll
    for (int it = 0; it < 4; ++it) {
        int f4 = tid + it * 256;
        int r  = f4 >> 4;
        int c4 = (f4 & 15) << 2;
        *(float4*)&((float(*)[DKH])bufKV)[r][c4] = *(const float4*)(Vc + (size_t)r * DKH + c4);
    }
    __syncthreads();

    const int t0  = tt0;
    const int dd0 = ss0;
    float ya[4][4], yb[4][4];
#pragma unroll
    for (int i = 0; i < 4; ++i)
#pragma unroll
        for (int j = 0; j < 4; ++j) { ya[i][j] = 0.0f; yb[i][j] = 0.0f; }
    const float (*Vs)[DKH] = (const float(*)[DKH])bufKV;
    for (int s = 0; s < CK; ++s) {
        float pr[4], vr[4];
#pragma unroll
        for (int i = 0; i < 4; ++i) pr[i] = Ps[t0 + i][s];
        *(float4*)vr = *(const float4*)&Vs[s][dd0];
#pragma unroll
        for (int i = 0; i < 4; ++i)
#pragma unroll
            for (int j = 0; j < 4; ++j) ya[i][j] += pr[i] * vr[j];
    }
    for (int e = 0; e < DKH; ++e) {
        float qr[4], sr[4];
#pragma unroll
        for (int i = 0; i < 4; ++i) qr[i] = Qs[t0 + i][e];
        *(float4*)sr = *(const float4*)&Sst[e][dd0];
#pragma unroll
        for (int i = 0; i < 4; ++i)
#pragma unroll
            for (int j = 0; j < 4; ++j) yb[i][j] += qr[i] * sr[j];
    }
#pragma unroll
    for (int i = 0; i < 4; ++i) {
        float g = __powf(gamma, (float)(t0 + i + 1));
        int tglob = c * CK + t0 + i;
        unsigned short* p = Y + ((size_t)(b * NL + tglob) * ND) + h * DKH + dd0;
        ushort4 o;
        o.x = f2bf(ya[i][0] + g * yb[i][0]);
        o.y = f2bf(ya[i][1] + g * yb[i][1]);
        o.z = f2bf(ya[i][2] + g * yb[i][2]);
        o.w = f2bf(ya[i][3] + g * yb[i][3]);
        *(ushort4*)p = o;
    }
}

extern "C" void kernel_launch(void* const* d_in, const int* in_sizes, int n_in,
                              void* d_out, int out_size, void* d_ws, size_t ws_size,
                              hipStream_t stream)
{
    (void)in_sizes; (void)n_in; (void)out_size; (void)ws_size;
    const float* x  = (const float*)d_in[0];
    const float* Wq = (const float*)d_in[1];
    const float* Wo = (const float*)d_in[2];
    const float* lg = (const float*)d_in[3];
    float* out = (float*)d_out;

    const size_t SZ = (size_t)NB * NH * NL * DKH;     // 8M floats = 32 MB
    float* Qb = (float*)d_ws;
    float* Kb = Qb + SZ;
    float* Vb = Kb + SZ;
    float* SL = Vb + SZ;                               // 8M floats (32 MB); aliased below pre-chunk_state
    unsigned short* Ybb = (unsigned short*)(SL + SZ);  // 8M bf16 = 16 MB
    unsigned short* Wob = Ybb + SZ;                    // 1M bf16 = 2 MB
    // phase-1 aliases inside SL region (dead once qkv_gemm completes):
    unsigned short* xb  = (unsigned short*)SL;         // 8M bf16 = 16 MB
    unsigned short* Wqb = xb + SZ;                     // 3M bf16 = 6 MB

    k_cast_bf16<<<2048, 256, 0, stream>>>(x,  xb,  (int)(SZ / 4));
    k_cast_bf16<<<1024, 256, 0, stream>>>(Wq, Wqb, (int)(3 * ND * ND / 4));
    k_cast_bf16<<<512,  256, 0, stream>>>(Wo, Wob, (int)(ND * ND / 4));

    k_gemm_qkv_bf16<<<dim3(3 * ND / 128, NM / 128), 256, 0, stream>>>(xb, Wqb, Qb, Kb, Vb);
    k_ln<<<dim3(NB * NH * NL / 4), 256, 0, stream>>>(Kb);
    k_chunk_state<<<dim3(NB * NH * NCH), 256, 0, stream>>>(Kb, Vb, lg, SL);
    k_scan<<<dim3(NB * NH, 4), 256, 0, stream>>>(SL, lg);
    k_chunk_out<<<dim3(NB * NH * NCH), 256, 0, stream>>>(Qb, Kb, Vb, SL, lg, Ybb);
    k_gemm_out_bf16<<<dim3(ND / 128, NM / 128), 256, 0, stream>>>(Ybb, Wob, out);
}

// Round 3
// 173.707 us; speedup vs baseline: 5.8731x; 1.6370x over previous
//
#include <hip/hip_runtime.h>
#include <cstddef>

// RetNetAttention round 3: bf16 end-to-end. MFMA chunk kernels with T2 XOR-swizzled LDS.
#define NB 2
#define NL 4096
#define ND 1024
#define NH 16
#define DKH 64
#define CK 64
#define NCH (NL / CK)
#define NM (NB * NL)
#define KD 1024

typedef __attribute__((ext_vector_type(8))) short bf16x8;
typedef __attribute__((ext_vector_type(4))) float f32x4;

__device__ __forceinline__ float dsigmoid(float x) { return 1.0f / (1.0f + __expf(-x)); }
__device__ __forceinline__ float bf2f(unsigned short u) { return __uint_as_float((unsigned)u << 16); }
__device__ __forceinline__ unsigned short f2bf(float f) {
    unsigned u = __float_as_uint(f);
    u = (u + 0x7fffu + ((u >> 16) & 1u)) >> 16;
    return (unsigned short)u;
}
// ushort-element index into a [64][64] tile with T2 bank swizzle
__device__ __forceinline__ int swz(int row, int col) { return row * 64 + (col ^ ((row & 7) << 3)); }

__device__ __forceinline__ void gload16(const void* g, void* l) {
    __builtin_amdgcn_global_load_lds(
        (const __attribute__((address_space(1))) unsigned int*)g,
        (__attribute__((address_space(3))) unsigned int*)l, 16, 0, 0);
}

// ================= fp32 -> bf16 cast =================
__global__ __launch_bounds__(256)
void k_cast_bf16(const float* __restrict__ in, unsigned short* __restrict__ out, int n4)
{
    int i = blockIdx.x * 256 + threadIdx.x;
    int stride = gridDim.x * 256;
    for (; i < n4; i += stride) {
        float4 v = ((const float4*)in)[i];
        ushort4 o;
        o.x = f2bf(v.x); o.y = f2bf(v.y); o.z = f2bf(v.z); o.w = f2bf(v.w);
        ((ushort4*)out)[i] = o;
    }
}

// ====== QKV GEMM (NT, bf16 MFMA, m97 structure), writes bf16 Q/K/V in (B,H,L,dk) ======
__global__ __launch_bounds__(256)
void k_gemm_qkv_bf16(const unsigned short* __restrict__ A, const unsigned short* __restrict__ Bm,
                     unsigned short* __restrict__ Qb, unsigned short* __restrict__ Kb,
                     unsigned short* __restrict__ Vb)
{
    __shared__ short As[128 * 32];
    __shared__ short Bs[128 * 32];
    const int tid = threadIdx.x;
    const int w = tid >> 6, lane = tid & 63;
    const int wr = w >> 1, wc = w & 1;
    const int lr = lane & 15, lk = lane >> 4;
    const int row0 = blockIdx.y * 128, col0 = blockIdx.x * 128;

    const unsigned short* gA = A + (size_t)(row0 + (tid >> 2)) * KD + (tid & 3) * 8;
    const unsigned short* gB = Bm + (size_t)(col0 + (tid >> 2)) * KD + (tid & 3) * 8;
    short* lA0 = As + w * 512;
    short* lA1 = As + 2048 + w * 512;
    short* lB0 = Bs + w * 512;
    short* lB1 = Bs + 2048 + w * 512;

    f32x4 acc[4][4];
#pragma unroll
    for (int m = 0; m < 4; ++m)
#pragma unroll
        for (int n = 0; n < 4; ++n) acc[m][n] = (f32x4){0.f, 0.f, 0.f, 0.f};

    const int aoff = (wr * 64 + lr) * 32 + lk * 8;
    const int boff = (wc * 64 + lr) * 32 + lk * 8;

    for (int k0 = 0; k0 < KD; k0 += 32) {
        gload16(gA + k0, lA0);
        gload16(gA + (size_t)64 * KD + k0, lA1);
        gload16(gB + k0, lB0);
        gload16(gB + (size_t)64 * KD + k0, lB1);
        __syncthreads();
        bf16x8 a[4], b[4];
#pragma unroll
        for (int m = 0; m < 4; ++m) a[m] = *(const bf16x8*)(As + aoff + m * 512);
#pragma unroll
        for (int n = 0; n < 4; ++n) b[n] = *(const bf16x8*)(Bs + boff + n * 512);
#pragma unroll
        for (int m = 0; m < 4; ++m)
#pragma unroll
            for (int n = 0; n < 4; ++n)
                acc[m][n] = __builtin_amdgcn_mfma_f32_16x16x32_bf16(a[m], b[n], acc[m][n], 0, 0, 0);
        __syncthreads();
    }

#pragma unroll
    for (int m = 0; m < 4; ++m) {
        const int mrow0 = row0 + wr * 64 + m * 16 + lk * 4;
#pragma unroll
        for (int n = 0; n < 4; ++n) {
            const int gcol = col0 + wc * 64 + n * 16 + lr;
            const int three = gcol >> 10;
            const int h = (gcol >> 6) & (NH - 1);
            const int d = gcol & (DKH - 1);
            unsigned short* dst = (three == 0) ? Qb : ((three == 1) ? Kb : Vb);
#pragma unroll
            for (int j = 0; j < 4; ++j) {
                const int mr = mrow0 + j;
                const int b = mr >> 12;
                const int t = mr & (NL - 1);
                dst[(((size_t)b * NH + h) * NL + t) * DKH + d] = f2bf(acc[m][n][j]);
            }
        }
    }
}

// ====== output GEMM (NT, bf16 MFMA), fp32 C ======
__global__ __launch_bounds__(256)
void k_gemm_out_bf16(const unsigned short* __restrict__ A, const unsigned short* __restrict__ Bm,
                     float* __restrict__ C)
{
    __shared__ short As[128 * 32];
    __shared__ short Bs[128 * 32];
    const int tid = threadIdx.x;
    const int w = tid >> 6, lane = tid & 63;
    const int wr = w >> 1, wc = w & 1;
    const int lr = lane & 15, lk = lane >> 4;
    const int row0 = blockIdx.y * 128, col0 = blockIdx.x * 128;

    const unsigned short* gA = A + (size_t)(row0 + (tid >> 2)) * KD + (tid & 3) * 8;
    const unsigned short* gB = Bm + (size_t)(col0 + (tid >> 2)) * KD + (tid & 3) * 8;
    short* lA0 = As + w * 512;
    short* lA1 = As + 2048 + w * 512;
    short* lB0 = Bs + w * 512;
    short* lB1 = Bs + 2048 + w * 512;

    f32x4 acc[4][4];
#pragma unroll
    for (int m = 0; m < 4; ++m)
#pragma unroll
        for (int n = 0; n < 4; ++n) acc[m][n] = (f32x4){0.f, 0.f, 0.f, 0.f};

    const int aoff = (wr * 64 + lr) * 32 + lk * 8;
    const int boff = (wc * 64 + lr) * 32 + lk * 8;

    for (int k0 = 0; k0 < KD; k0 += 32) {
        gload16(gA + k0, lA0);
        gload16(gA + (size_t)64 * KD + k0, lA1);
        gload16(gB + k0, lB0);
        gload16(gB + (size_t)64 * KD + k0, lB1);
        __syncthreads();
        bf16x8 a[4], b[4];
#pragma unroll
        for (int m = 0; m < 4; ++m) a[m] = *(const bf16x8*)(As + aoff + m * 512);
#pragma unroll
        for (int n = 0; n < 4; ++n) b[n] = *(const bf16x8*)(Bs + boff + n * 512);
#pragma unroll
        for (int m = 0; m < 4; ++m)
#pragma unroll
            for (int n = 0; n < 4; ++n)
                acc[m][n] = __builtin_amdgcn_mfma_f32_16x16x32_bf16(a[m], b[n], acc[m][n], 0, 0, 0);
        __syncthreads();
    }

#pragma unroll
    for (int m = 0; m < 4; ++m) {
        const int mrow0 = row0 + wr * 64 + m * 16 + lk * 4;
#pragma unroll
        for (int n = 0; n < 4; ++n) {
            const int gcol = col0 + wc * 64 + n * 16 + lr;
#pragma unroll
            for (int j = 0; j < 4; ++j)
                C[(size_t)(mrow0 + j) * ND + gcol] = acc[m][n][j];
        }
    }
}

// ================= LayerNorm over dk=64 (bf16 in place, one wave per row) =================
__global__ __launch_bounds__(256)
void k_ln(unsigned short* __restrict__ Kb)
{
    int row  = blockIdx.x * 4 + (threadIdx.x >> 6);
    int lane = threadIdx.x & 63;
    unsigned short* p = Kb + (size_t)row * DKH + lane;
    float x = bf2f(*p);
    float s = x;
#pragma unroll
    for (int o = 32; o > 0; o >>= 1) s += __shfl_xor(s, o);
    float mu = s * (1.0f / 64.0f);
    float dv = x - mu;
    float q = dv * dv;
#pragma unroll
    for (int o = 32; o > 0; o >>= 1) q += __shfl_xor(q, o);
    float rstd = rsqrtf(q * (1.0f / 64.0f) + 1e-5f);
    *p = f2bf(dv * rstd);
}

// ====== per-chunk local state via MFMA: SL[d][e] = sum_s g^{63-s} v_s[d] k_s[e] (bf16) ======
__global__ __launch_bounds__(256)
void k_chunk_state(const unsigned short* __restrict__ Kb, const unsigned short* __restrict__ Vb,
                   const float* __restrict__ lg, unsigned short* __restrict__ SL)
{
    __shared__ unsigned short Kt[64 * 64];  // K^T[e][s], swizzled
    __shared__ unsigned short Vt[64 * 64];  // (g^{63-s} V)^T[d][s], swizzled
    const int blk = blockIdx.x;
    const int c   = blk & (NCH - 1);
    const int bh  = blk >> 6;
    const int h   = bh & (NH - 1);
    const float gamma = dsigmoid(lg[h]);
    const float l2g = log2f(gamma);
    const int tid = threadIdx.x;
    const unsigned short* Kc = Kb + ((size_t)bh * NL + c * CK) * DKH;
    const unsigned short* Vc = Vb + ((size_t)bh * NL + c * CK) * DKH;

#pragma unroll
    for (int it = 0; it < 2; ++it) {
        int idx = tid + it * 256;
        int r   = idx & 63;
        int c0  = (idx >> 6) * 8;
        bf16x8 k8 = *(const bf16x8*)(Kc + (size_t)r * DKH + c0);
        bf16x8 v8 = *(const bf16x8*)(Vc + (size_t)r * DKH + c0);
        float wgt = exp2f((float)(CK - 1 - r) * l2g);
#pragma unroll
        for (int j = 0; j < 8; ++j) {
            Kt[swz(c0 + j, r)] = (unsigned short)k8[j];
            Vt[swz(c0 + j, r)] = f2bf(bf2f((unsigned short)v8[j]) * wgt);
        }
    }
    __syncthreads();

    const int w = tid >> 6, lane = tid & 63;
    const int wr = w >> 1, wc = w & 1;
    const int lr = lane & 15, lk = lane >> 4;
    f32x4 acc[2][2];
#pragma unroll
    for (int m = 0; m < 2; ++m)
#pragma unroll
        for (int n = 0; n < 2; ++n) acc[m][n] = (f32x4){0.f, 0.f, 0.f, 0.f};
#pragma unroll
    for (int kk = 0; kk < 2; ++kk) {
        const int so = kk * 32 + lk * 8;
        bf16x8 a[2], b[2];
#pragma unroll
        for (int m = 0; m < 2; ++m) a[m] = *(const bf16x8*)&Vt[swz(wr * 32 + m * 16 + lr, so)];
#pragma unroll
        for (int n = 0; n < 2; ++n) b[n] = *(const bf16x8*)&Kt[swz(wc * 32 + n * 16 + lr, so)];
#pragma unroll
        for (int m = 0; m < 2; ++m)
#pragma unroll
            for (int n = 0; n < 2; ++n)
                acc[m][n] = __builtin_amdgcn_mfma_f32_16x16x32_bf16(a[m], b[n], acc[m][n], 0, 0, 0);
    }

    unsigned short* out = SL + (size_t)blk * (DKH * DKH);
#pragma unroll
    for (int m = 0; m < 2; ++m)
#pragma unroll
        for (int n = 0; n < 2; ++n)
#pragma unroll
            for (int j = 0; j < 4; ++j) {
                int d = wr * 32 + m * 16 + lk * 4 + j;
                int e = wc * 32 + n * 16 + lr;
                out[d * DKH + e] = f2bf(acc[m][n][j]);
            }
}

// ====== sequential scan over chunks: SS[c] = state BEFORE chunk c (bf16 io, fp32 accum) ======
__global__ __launch_bounds__(256)
void k_scan(const unsigned short* __restrict__ SL, const float* __restrict__ lg,
            unsigned short* __restrict__ SS)
{
    const int bh = blockIdx.x;
    const int qt = blockIdx.y;
    const int h  = bh & (NH - 1);
    const float gamma = dsigmoid(lg[h]);
    const float dc = __powf(gamma, (float)CK);
    const size_t base = (size_t)bh * NCH * (DKH * DKH) + qt * 1024 + threadIdx.x * 4;
    float s0 = 0.f, s1 = 0.f, s2 = 0.f, s3 = 0.f;
    for (int c = 0; c < NCH; ++c) {
        const size_t off = base + (size_t)c * (DKH * DKH);
        ushort4 l = *(const ushort4*)(SL + off);
        ushort4 o;
        o.x = f2bf(s0); o.y = f2bf(s1); o.z = f2bf(s2); o.w = f2bf(s3);
        *(ushort4*)(SS + off) = o;
        s0 = s0 * dc + bf2f(l.x); s1 = s1 * dc + bf2f(l.y);
        s2 = s2 * dc + bf2f(l.z); s3 = s3 * dc + bf2f(l.w);
    }
}

// ====== per-chunk output via MFMA: Y = mask(QK^T)V + g^{t+1} Q S^T, bf16 out ======
__global__ __launch_bounds__(256)
void k_chunk_out(const unsigned short* __restrict__ Qb, const unsigned short* __restrict__ Kb,
                 const unsigned short* __restrict__ Vb, const unsigned short* __restrict__ SS,
                 const float* __restrict__ lg, unsigned short* __restrict__ Y)
{
    __shared__ unsigned short Qs[64 * 64];  // Q[t][e] swizzled
    __shared__ unsigned short Ks[64 * 64];  // K[s][e] swizzled
    __shared__ unsigned short Vt[64 * 64];  // V^T[d][s] swizzled
    __shared__ unsigned short Ss[64 * 64];  // S[d][e] swizzled
    __shared__ unsigned short Ps[64 * 64];  // P[t][s] swizzled
    const int blk = blockIdx.x;
    const int c   = blk & (NCH - 1);
    const int bh  = blk >> 6;
    const int h   = bh & (NH - 1);
    const int b   = bh >> 4;
    const float gamma = dsigmoid(lg[h]);
    const float l2g = log2f(gamma);
    const int tid = threadIdx.x;
    const unsigned short* Qc = Qb + ((size_t)bh * NL + c * CK) * DKH;
    const unsigned short* Kc = Kb + ((size_t)bh * NL + c * CK) * DKH;
    const unsigned short* Vc = Vb + ((size_t)bh * NL + c * CK) * DKH;
    const unsigned short* Sc = SS + (size_t)blk * (DKH * DKH);

#pragma unroll
    for (int it = 0; it < 2; ++it) {
        int idx = tid + it * 256;
        int r   = idx & 63;
        int c0  = (idx >> 6) * 8;
        bf16x8 q8 = *(const bf16x8*)(Qc + (size_t)r * DKH + c0);
        bf16x8 k8 = *(const bf16x8*)(Kc + (size_t)r * DKH + c0);
        bf16x8 s8 = *(const bf16x8*)(Sc + (size_t)r * DKH + c0);
        bf16x8 v8 = *(const bf16x8*)(Vc + (size_t)r * DKH + c0);
        *(bf16x8*)&Qs[swz(r, c0)] = q8;
        *(bf16x8*)&Ks[swz(r, c0)] = k8;
        *(bf16x8*)&Ss[swz(r, c0)] = s8;
#pragma unroll
        for (int j = 0; j < 8; ++j) Vt[swz(c0 + j, r)] = (unsigned short)v8[j];
    }
    __syncthreads();

    const int w = tid >> 6, lane = tid & 63;
    const int wr = w >> 1, wc = w & 1;
    const int lr = lane & 15, lk = lane >> 4;

    // phase A: P = Q K^T with causal decay mask
    f32x4 accp[2][2];
#pragma unroll
    for (int m = 0; m < 2; ++m)
#pragma unroll
        for (int n = 0; n < 2; ++n) accp[m][n] = (f32x4){0.f, 0.f, 0.f, 0.f};
#pragma unroll
    for (int kk = 0; kk < 2; ++kk) {
        const int eo = kk * 32 + lk * 8;
        bf16x8 a[2], bfr[2];
#pragma unroll
        for (int m = 0; m < 2; ++m) a[m]   = *(const bf16x8*)&Qs[swz(wr * 32 + m * 16 + lr, eo)];
#pragma unroll
        for (int n = 0; n < 2; ++n) bfr[n] = *(const bf16x8*)&Ks[swz(wc * 32 + n * 16 + lr, eo)];
#pragma unroll
        for (int m = 0; m < 2; ++m)
#pragma unroll
            for (int n = 0; n < 2; ++n)
                accp[m][n] = __builtin_amdgcn_mfma_f32_16x16x32_bf16(a[m], bfr[n], accp[m][n], 0, 0, 0);
    }
#pragma unroll
    for (int m = 0; m < 2; ++m)
#pragma unroll
        for (int n = 0; n < 2; ++n)
#pragma unroll
            for (int j = 0; j < 4; ++j) {
                int t = wr * 32 + m * 16 + lk * 4 + j;
                int s = wc * 32 + n * 16 + lr;
                int dt = t - s;
                float v = (dt >= 0) ? accp[m][n][j] * exp2f((float)dt * l2g) : 0.0f;
                Ps[swz(t, s)] = f2bf(v);
            }
    __syncthreads();

    // phase B: Y = P V + g^{t+1} Q S^T
    f32x4 accy[2][2], accz[2][2];
#pragma unroll
    for (int m = 0; m < 2; ++m)
#pragma unroll
        for (int n = 0; n < 2; ++n) {
            accy[m][n] = (f32x4){0.f, 0.f, 0.f, 0.f};
            accz[m][n] = (f32x4){0.f, 0.f, 0.f, 0.f};
        }
#pragma unroll
    for (int kk = 0; kk < 2; ++kk) {
        const int so = kk * 32 + lk * 8;
        bf16x8 pa[2], qa[2], vb[2], sb[2];
#pragma unroll
        for (int m = 0; m < 2; ++m) {
            pa[m] = *(const bf16x8*)&Ps[swz(wr * 32 + m * 16 + lr, so)];
            qa[m] = *(const bf16x8*)&Qs[swz(wr * 32 + m * 16 + lr, so)];
        }
#pragma unroll
        for (int n = 0; n < 2; ++n) {
            vb[n] = *(const bf16x8*)&Vt[swz(wc * 32 + n * 16 + lr, so)];
            sb[n] = *(const bf16x8*)&Ss[swz(wc * 32 + n * 16 + lr, so)];
        }
#pragma unroll
        for (int m = 0; m < 2; ++m)
#pragma unroll
            for (int n = 0; n < 2; ++n) {
                accy[m][n] = __builtin_amdgcn_mfma_f32_16x16x32_bf16(pa[m], vb[n], accy[m][n], 0, 0, 0);
                accz[m][n] = __builtin_amdgcn_mfma_f32_16x16x32_bf16(qa[m], sb[n], accz[m][n], 0, 0, 0);
            }
    }

#pragma unroll
    for (int m = 0; m < 2; ++m)
#pragma unroll
        for (int n = 0; n < 2; ++n)
#pragma unroll
            for (int j = 0; j < 4; ++j) {
                int t = wr * 32 + m * 16 + lk * 4 + j;
                int d = wc * 32 + n * 16 + lr;
                float g = exp2f((float)(t + 1) * l2g);
                float y = accy[m][n][j] + g * accz[m][n][j];
                int tg = c * CK + t;
                Y[((size_t)(b * NL + tg)) * ND + h * DKH + d] = f2bf(y);
            }
}

extern "C" void kernel_launch(void* const* d_in, const int* in_sizes, int n_in,
                              void* d_out, int out_size, void* d_ws, size_t ws_size,
                              hipStream_t stream)
{
    (void)in_sizes; (void)n_in; (void)out_size; (void)ws_size;
    const float* x  = (const float*)d_in[0];
    const float* Wq = (const float*)d_in[1];
    const float* Wo = (const float*)d_in[2];
    const float* lg = (const float*)d_in[3];
    float* out = (float*)d_out;

    const size_t SZ = (size_t)NB * NH * NL * DKH;      // 8M elements
    unsigned short* xb  = (unsigned short*)d_ws;       // 16 MB
    unsigned short* Wqb = xb + SZ;                     // 6 MB
    unsigned short* Wob = Wqb + (size_t)3 * ND * ND;   // 2 MB
    unsigned short* Qb  = Wob + (size_t)ND * ND;
    unsigned short* Kb  = Qb + SZ;
    unsigned short* Vb  = Kb + SZ;
    unsigned short* SL  = Vb + SZ;
    unsigned short* SS  = SL + SZ;
    unsigned short* Ybb = SS + SZ;                     // total 120 MB

    k_cast_bf16<<<1024, 256, 0, stream>>>(x,  xb,  (int)(SZ / 4));
    k_cast_bf16<<<1024, 256, 0, stream>>>(Wq, Wqb, (int)(3 * ND * ND / 4));
    k_cast_bf16<<<512,  256, 0, stream>>>(Wo, Wob, (int)(ND * ND / 4));

    k_gemm_qkv_bf16<<<dim3(3 * ND / 128, NM / 128), 256, 0, stream>>>(xb, Wqb, Qb, Kb, Vb);
    k_ln<<<dim3(NB * NH * NL / 4), 256, 0, stream>>>(Kb);
    k_chunk_state<<<dim3(NB * NH * NCH), 256, 0, stream>>>(Kb, Vb, lg, SL);
    k_scan<<<dim3(NB * NH, 4), 256, 0, stream>>>(SL, lg, SS);
    k_chunk_out<<<dim3(NB * NH * NCH), 256, 0, stream>>>(Qb, Kb, Vb, SS, lg, Ybb);
    k_gemm_out_bf16<<<dim3(ND / 128, NM / 128), 256, 0, stream>>>(Ybb, Wob, out);
}

// Round 4
// 135.332 us; speedup vs baseline: 7.5385x; 1.2836x over previous
//
#include <hip/hip_runtime.h>
#include <cstddef>

// RetNetAttention round 4: BK=64 swizzled GEMMs + T1 XCD swizzle, LN fused into
// chunk kernels, single cast kernel, coalesced Y writes.
#define NB 2
#define NL 4096
#define ND 1024
#define NH 16
#define DKH 64
#define CK 64
#define NCH (NL / CK)
#define NM (NB * NL)
#define KD 1024

typedef __attribute__((ext_vector_type(8))) short bf16x8;
typedef __attribute__((ext_vector_type(4))) float f32x4;

__device__ __forceinline__ float dsigmoid(float x) { return 1.0f / (1.0f + __expf(-x)); }
__device__ __forceinline__ float bf2f(unsigned short u) { return __uint_as_float((unsigned)u << 16); }
__device__ __forceinline__ unsigned short f2bf(float f) {
    unsigned u = __float_as_uint(f);
    u = (u + 0x7fffu + ((u >> 16) & 1u)) >> 16;
    return (unsigned short)u;
}
// element index into [R][64]-ushort tile, XOR-swizzled at 8-elem (16B) granularity
__device__ __forceinline__ int swz(int row, int col) { return row * 64 + (col ^ ((row & 7) << 3)); }

__device__ __forceinline__ void gload16(const void* g, void* l) {
    __builtin_amdgcn_global_load_lds(
        (const __attribute__((address_space(1))) unsigned int*)g,
        (__attribute__((address_space(3))) unsigned int*)l, 16, 0, 0);
}

// ================= fused fp32 -> bf16 casts =================
__global__ __launch_bounds__(256)
void k_cast_all(const float* __restrict__ x, const float* __restrict__ Wq,
                const float* __restrict__ Wo, unsigned short* __restrict__ xb,
                unsigned short* __restrict__ Wqb, unsigned short* __restrict__ Wob)
{
    const int N1 = NB * NL * ND / 4;
    const int N2 = 3 * ND * ND / 4;
    const int N3 = ND * ND / 4;
    const int total = N1 + N2 + N3;
    int i = blockIdx.x * 256 + threadIdx.x;
    const int stride = gridDim.x * 256;
    for (; i < total; i += stride) {
        const float4* src;
        ushort4* dst;
        int j;
        if (i < N1)            { src = (const float4*)x;  dst = (ushort4*)xb;  j = i; }
        else if (i < N1 + N2)  { src = (const float4*)Wq; dst = (ushort4*)Wqb; j = i - N1; }
        else                   { src = (const float4*)Wo; dst = (ushort4*)Wob; j = i - N1 - N2; }
        float4 v = src[j];
        ushort4 o;
        o.x = f2bf(v.x); o.y = f2bf(v.y); o.z = f2bf(v.z); o.w = f2bf(v.w);
        dst[j] = o;
    }
}

// ====== bf16 MFMA GEMM (NT), 128x128 tile, BK=64, swizzled LDS reads ======
// staging: lane fetches pre-swizzled global chunk so linear gload_lds dest lands swizzled.

__global__ __launch_bounds__(256)
void k_gemm_qkv_bf16(const unsigned short* __restrict__ A, const unsigned short* __restrict__ Bm,
                     unsigned short* __restrict__ Qb, unsigned short* __restrict__ Kb,
                     unsigned short* __restrict__ Vb)
{
    __shared__ short As[128 * 64];
    __shared__ short Bs[128 * 64];
    const int tid = threadIdx.x;
    const int w = tid >> 6, lane = tid & 63;
    const int wr = w >> 1, wc = w & 1;
    const int lr = lane & 15, lk = lane >> 4;

    // T1 bijective XCD swizzle (nwg % 8 == 0)
    const int nbx = gridDim.x;
    const int nwg = nbx * gridDim.y;
    const int bid = blockIdx.y * nbx + blockIdx.x;
    const int sb  = (bid & 7) * (nwg >> 3) + (bid >> 3);
    const int row0 = (sb / nbx) * 128, col0 = (sb % nbx) * 128;

    const int srow = tid >> 3;                         // 0..31
    const int schk = (tid & 7) ^ (srow & 7);           // pre-swizzled source chunk
    const unsigned short* gA = A + (size_t)(row0 + srow) * KD + schk * 8;
    const unsigned short* gB = Bm + (size_t)(col0 + srow) * KD + schk * 8;
    short* lA = As + (w * 8) * 64;
    short* lB = Bs + (w * 8) * 64;

    f32x4 acc[4][4];
#pragma unroll
    for (int m = 0; m < 4; ++m)
#pragma unroll
        for (int n = 0; n < 4; ++n) acc[m][n] = (f32x4){0.f, 0.f, 0.f, 0.f};

    int arow[4], brow[4];
#pragma unroll
    for (int m = 0; m < 4; ++m) arow[m] = (wr * 64 + m * 16 + lr) * 64;
#pragma unroll
    for (int n = 0; n < 4; ++n) brow[n] = (wc * 64 + n * 16 + lr) * 64;
    const int xr = lr & 7;
    const int coff0 = ((0 * 4 + lk) ^ xr) * 8;
    const int coff1 = ((1 * 4 + lk) ^ xr) * 8;

    for (int k0 = 0; k0 < KD; k0 += 64) {
#pragma unroll
        for (int i = 0; i < 4; ++i) gload16(gA + (size_t)(i * 32) * KD + k0, lA + i * 2048);
#pragma unroll
        for (int i = 0; i < 4; ++i) gload16(gB + (size_t)(i * 32) * KD + k0, lB + i * 2048);
        __syncthreads();
#pragma unroll
        for (int kk = 0; kk < 2; ++kk) {
            const int co = kk ? coff1 : coff0;
            bf16x8 a[4], b[4];
#pragma unroll
            for (int m = 0; m < 4; ++m) a[m] = *(const bf16x8*)(As + arow[m] + co);
#pragma unroll
            for (int n = 0; n < 4; ++n) b[n] = *(const bf16x8*)(Bs + brow[n] + co);
#pragma unroll
            for (int m = 0; m < 4; ++m)
#pragma unroll
                for (int n = 0; n < 4; ++n)
                    acc[m][n] = __builtin_amdgcn_mfma_f32_16x16x32_bf16(a[m], b[n], acc[m][n], 0, 0, 0);
        }
        __syncthreads();
    }

#pragma unroll
    for (int m = 0; m < 4; ++m) {
        const int mrow0 = row0 + wr * 64 + m * 16 + lk * 4;
#pragma unroll
        for (int n = 0; n < 4; ++n) {
            const int gcol = col0 + wc * 64 + n * 16 + lr;
            const int three = gcol >> 10;
            const int h = (gcol >> 6) & (NH - 1);
            const int d = gcol & (DKH - 1);
            unsigned short* dst = (three == 0) ? Qb : ((three == 1) ? Kb : Vb);
#pragma unroll
            for (int j = 0; j < 4; ++j) {
                const int mr = mrow0 + j;
                const int b = mr >> 12;
                const int t = mr & (NL - 1);
                dst[(((size_t)b * NH + h) * NL + t) * DKH + d] = f2bf(acc[m][n][j]);
            }
        }
    }
}

__global__ __launch_bounds__(256)
void k_gemm_out_bf16(const unsigned short* __restrict__ A, const unsigned short* __restrict__ Bm,
                     float* __restrict__ C)
{
    __shared__ short As[128 * 64];
    __shared__ short Bs[128 * 64];
    const int tid = threadIdx.x;
    const int w = tid >> 6, lane = tid & 63;
    const int wr = w >> 1, wc = w & 1;
    const int lr = lane & 15, lk = lane >> 4;

    const int nbx = gridDim.x;
    const int nwg = nbx * gridDim.y;
    const int bid = blockIdx.y * nbx + blockIdx.x;
    const int sb  = (bid & 7) * (nwg >> 3) + (bid >> 3);
    const int row0 = (sb / nbx) * 128, col0 = (sb % nbx) * 128;

    const int srow = tid >> 3;
    const int schk = (tid & 7) ^ (srow & 7);
    const unsigned short* gA = A + (size_t)(row0 + srow) * KD + schk * 8;
    const unsigned short* gB = Bm + (size_t)(col0 + srow) * KD + schk * 8;
    short* lA = As + (w * 8) * 64;
    short* lB = Bs + (w * 8) * 64;

    f32x4 acc[4][4];
#pragma unroll
    for (int m = 0; m < 4; ++m)
#pragma unroll
        for (int n = 0; n < 4; ++n) acc[m][n] = (f32x4){0.f, 0.f, 0.f, 0.f};

    int arow[4], brow[4];
#pragma unroll
    for (int m = 0; m < 4; ++m) arow[m] = (wr * 64 + m * 16 + lr) * 64;
#pragma unroll
    for (int n = 0; n < 4; ++n) brow[n] = (wc * 64 + n * 16 + lr) * 64;
    const int xr = lr & 7;
    const int coff0 = ((0 * 4 + lk) ^ xr) * 8;
    const int coff1 = ((1 * 4 + lk) ^ xr) * 8;

    for (int k0 = 0; k0 < KD; k0 += 64) {
#pragma unroll
        for (int i = 0; i < 4; ++i) gload16(gA + (size_t)(i * 32) * KD + k0, lA + i * 2048);
#pragma unroll
        for (int i = 0; i < 4; ++i) gload16(gB + (size_t)(i * 32) * KD + k0, lB + i * 2048);
        __syncthreads();
#pragma unroll
        for (int kk = 0; kk < 2; ++kk) {
            const int co = kk ? coff1 : coff0;
            bf16x8 a[4], b[4];
#pragma unroll
            for (int m = 0; m < 4; ++m) a[m] = *(const bf16x8*)(As + arow[m] + co);
#pragma unroll
            for (int n = 0; n < 4; ++n) b[n] = *(const bf16x8*)(Bs + brow[n] + co);
#pragma unroll
            for (int m = 0; m < 4; ++m)
#pragma unroll
                for (int n = 0; n < 4; ++n)
                    acc[m][n] = __builtin_amdgcn_mfma_f32_16x16x32_bf16(a[m], b[n], acc[m][n], 0, 0, 0);
        }
        __syncthreads();
    }

#pragma unroll
    for (int m = 0; m < 4; ++m) {
        const int mrow0 = row0 + wr * 64 + m * 16 + lk * 4;
#pragma unroll
        for (int n = 0; n < 4; ++n) {
            const int gcol = col0 + wc * 64 + n * 16 + lr;
#pragma unroll
            for (int j = 0; j < 4; ++j)
                C[(size_t)(mrow0 + j) * ND + gcol] = acc[m][n][j];
        }
    }
}

// ====== per-chunk local state (LN fused): SL[d][e] = sum_s g^{63-s} v_s[d] ln(k_s)[e] ======
__global__ __launch_bounds__(256)
void k_chunk_state(const unsigned short* __restrict__ Kb, const unsigned short* __restrict__ Vb,
                   const float* __restrict__ lg, unsigned short* __restrict__ SL)
{
    __shared__ unsigned short Kt[64 * 64];
    __shared__ unsigned short Vt[64 * 64];
    __shared__ float red[64][8];
    const int blk = blockIdx.x;
    const int c   = blk & (NCH - 1);
    const int bh  = blk >> 6;
    const int h   = bh & (NH - 1);
    const float gamma = dsigmoid(lg[h]);
    const float l2g = log2f(gamma);
    const int tid = threadIdx.x;
    const unsigned short* Kc = Kb + ((size_t)bh * NL + c * CK) * DKH;
    const unsigned short* Vc = Vb + ((size_t)bh * NL + c * CK) * DKH;

    const int r  = tid & 63;
    const int w4 = tid >> 6;
    const int c0 = w4 * 8;
    bf16x8 k8a = *(const bf16x8*)(Kc + (size_t)r * DKH + c0);
    bf16x8 k8b = *(const bf16x8*)(Kc + (size_t)r * DKH + c0 + 32);
    bf16x8 v8a = *(const bf16x8*)(Vc + (size_t)r * DKH + c0);
    bf16x8 v8b = *(const bf16x8*)(Vc + (size_t)r * DKH + c0 + 32);
    float sum = 0.f, sq = 0.f;
#pragma unroll
    for (int j = 0; j < 8; ++j) {
        float xa = bf2f((unsigned short)k8a[j]); sum += xa; sq += xa * xa;
        float xb = bf2f((unsigned short)k8b[j]); sum += xb; sq += xb * xb;
    }
    red[r][w4] = sum; red[r][w4 + 4] = sq;
    __syncthreads();
    float s  = red[r][0] + red[r][1] + red[r][2] + red[r][3];
    float qq = red[r][4] + red[r][5] + red[r][6] + red[r][7];
    float mu = s * (1.0f / 64.0f);
    float rstd = rsqrtf(qq * (1.0f / 64.0f) - mu * mu + 1e-5f);
    float wgt = exp2f((float)(CK - 1 - r) * l2g);
#pragma unroll
    for (int j = 0; j < 8; ++j) {
        Kt[swz(c0 + j, r)]      = f2bf((bf2f((unsigned short)k8a[j]) - mu) * rstd);
        Kt[swz(c0 + 32 + j, r)] = f2bf((bf2f((unsigned short)k8b[j]) - mu) * rstd);
        Vt[swz(c0 + j, r)]      = f2bf(bf2f((unsigned short)v8a[j]) * wgt);
        Vt[swz(c0 + 32 + j, r)] = f2bf(bf2f((unsigned short)v8b[j]) * wgt);
    }
    __syncthreads();

    const int w = tid >> 6, lane = tid & 63;
    const int wr = w >> 1, wc = w & 1;
    const int lr = lane & 15, lk = lane >> 4;
    f32x4 acc[2][2];
#pragma unroll
    for (int m = 0; m < 2; ++m)
#pragma unroll
        for (int n = 0; n < 2; ++n) acc[m][n] = (f32x4){0.f, 0.f, 0.f, 0.f};
#pragma unroll
    for (int kk = 0; kk < 2; ++kk) {
        const int so = kk * 32 + lk * 8;
        bf16x8 a[2], b[2];
#pragma unroll
        for (int m = 0; m < 2; ++m) a[m] = *(const bf16x8*)&Vt[swz(wr * 32 + m * 16 + lr, so)];
#pragma unroll
        for (int n = 0; n < 2; ++n) b[n] = *(const bf16x8*)&Kt[swz(wc * 32 + n * 16 + lr, so)];
#pragma unroll
        for (int m = 0; m < 2; ++m)
#pragma unroll
            for (int n = 0; n < 2; ++n)
                acc[m][n] = __builtin_amdgcn_mfma_f32_16x16x32_bf16(a[m], b[n], acc[m][n], 0, 0, 0);
    }

    unsigned short* out = SL + (size_t)blk * (DKH * DKH);
#pragma unroll
    for (int m = 0; m < 2; ++m)
#pragma unroll
        for (int n = 0; n < 2; ++n)
#pragma unroll
            for (int j = 0; j < 4; ++j) {
                int d = wr * 32 + m * 16 + lk * 4 + j;
                int e = wc * 32 + n * 16 + lr;
                out[d * DKH + e] = f2bf(acc[m][n][j]);
            }
}

// ====== sequential scan over chunks: SS[c] = state BEFORE chunk c ======
__global__ __launch_bounds__(256)
void k_scan(const unsigned short* __restrict__ SL, const float* __restrict__ lg,
            unsigned short* __restrict__ SS)
{
    const int bh = blockIdx.x;
    const int qt = blockIdx.y;
    const int h  = bh & (NH - 1);
    const float gamma = dsigmoid(lg[h]);
    const float dc = __powf(gamma, (float)CK);
    const size_t base = (size_t)bh * NCH * (DKH * DKH) + qt * 1024 + threadIdx.x * 4;
    float s0 = 0.f, s1 = 0.f, s2 = 0.f, s3 = 0.f;
    for (int c = 0; c < NCH; ++c) {
        const size_t off = base + (size_t)c * (DKH * DKH);
        ushort4 l = *(const ushort4*)(SL + off);
        ushort4 o;
        o.x = f2bf(s0); o.y = f2bf(s1); o.z = f2bf(s2); o.w = f2bf(s3);
        *(ushort4*)(SS + off) = o;
        s0 = s0 * dc + bf2f(l.x); s1 = s1 * dc + bf2f(l.y);
        s2 = s2 * dc + bf2f(l.z); s3 = s3 * dc + bf2f(l.w);
    }
}

// ====== per-chunk output (LN fused): Y = mask(Q K^T)V + g^{t+1} Q S^T, coalesced bf16 out ======
__global__ __launch_bounds__(256)
void k_chunk_out(const unsigned short* __restrict__ Qb, const unsigned short* __restrict__ Kb,
                 const unsigned short* __restrict__ Vb, const unsigned short* __restrict__ SS,
                 const float* __restrict__ lg, unsigned short* __restrict__ Y)
{
    __shared__ unsigned short Qs[64 * 64];
    __shared__ unsigned short Ks[64 * 64];
    __shared__ unsigned short Vt[64 * 64];
    __shared__ unsigned short Ss[64 * 64];
    __shared__ unsigned short Ps[64 * 64];   // reused as Y-staging
    __shared__ float red[64][8];
    const int blk = blockIdx.x;
    const int c   = blk & (NCH - 1);
    const int bh  = blk >> 6;
    const int h   = bh & (NH - 1);
    const int b   = bh >> 4;
    const float gamma = dsigmoid(lg[h]);
    const float l2g = log2f(gamma);
    const int tid = threadIdx.x;
    const unsigned short* Qc = Qb + ((size_t)bh * NL + c * CK) * DKH;
    const unsigned short* Kc = Kb + ((size_t)bh * NL + c * CK) * DKH;
    const unsigned short* Vc = Vb + ((size_t)bh * NL + c * CK) * DKH;
    const unsigned short* Sc = SS + (size_t)blk * (DKH * DKH);

    const int r  = tid & 63;
    const int w4 = tid >> 6;
    const int c0 = w4 * 8;
    bf16x8 q8a = *(const bf16x8*)(Qc + (size_t)r * DKH + c0);
    bf16x8 q8b = *(const bf16x8*)(Qc + (size_t)r * DKH + c0 + 32);
    bf16x8 k8a = *(const bf16x8*)(Kc + (size_t)r * DKH + c0);
    bf16x8 k8b = *(const bf16x8*)(Kc + (size_t)r * DKH + c0 + 32);
    bf16x8 v8a = *(const bf16x8*)(Vc + (size_t)r * DKH + c0);
    bf16x8 v8b = *(const bf16x8*)(Vc + (size_t)r * DKH + c0 + 32);
    bf16x8 s8a = *(const bf16x8*)(Sc + (size_t)r * DKH + c0);
    bf16x8 s8b = *(const bf16x8*)(Sc + (size_t)r * DKH + c0 + 32);
    float sum = 0.f, sq = 0.f;
#pragma unroll
    for (int j = 0; j < 8; ++j) {
        float xa = bf2f((unsigned short)k8a[j]); sum += xa; sq += xa * xa;
        float xb = bf2f((unsigned short)k8b[j]); sum += xb; sq += xb * xb;
    }
    red[r][w4] = sum; red[r][w4 + 4] = sq;
    __syncthreads();
    float sm = red[r][0] + red[r][1] + red[r][2] + red[r][3];
    float qq = red[r][4] + red[r][5] + red[r][6] + red[r][7];
    float mu = sm * (1.0f / 64.0f);
    float rstd = rsqrtf(qq * (1.0f / 64.0f) - mu * mu + 1e-5f);
    *(bf16x8*)&Qs[swz(r, c0)]      = q8a;
    *(bf16x8*)&Qs[swz(r, c0 + 32)] = q8b;
    *(bf16x8*)&Ss[swz(r, c0)]      = s8a;
    *(bf16x8*)&Ss[swz(r, c0 + 32)] = s8b;
#pragma unroll
    for (int j = 0; j < 8; ++j) {
        Ks[swz(r, c0 + j)]      = f2bf((bf2f((unsigned short)k8a[j]) - mu) * rstd);
        Ks[swz(r, c0 + 32 + j)] = f2bf((bf2f((unsigned short)k8b[j]) - mu) * rstd);
        Vt[swz(c0 + j, r)]      = (unsigned short)v8a[j];
        Vt[swz(c0 + 32 + j, r)] = (unsigned short)v8b[j];
    }
    __syncthreads();

    const int w = tid >> 6, lane = tid & 63;
    const int wr = w >> 1, wc = w & 1;
    const int lr = lane & 15, lk = lane >> 4;

    // phase A: P = Q K^T with causal decay
    f32x4 accp[2][2];
#pragma unroll
    for (int m = 0; m < 2; ++m)
#pragma unroll
        for (int n = 0; n < 2; ++n) accp[m][n] = (f32x4){0.f, 0.f, 0.f, 0.f};
#pragma unroll
    for (int kk = 0; kk < 2; ++kk) {
        const int eo = kk * 32 + lk * 8;
        bf16x8 a[2], bfr[2];
#pragma unroll
        for (int m = 0; m < 2; ++m) a[m]   = *(const bf16x8*)&Qs[swz(wr * 32 + m * 16 + lr, eo)];
#pragma unroll
        for (int n = 0; n < 2; ++n) bfr[n] = *(const bf16x8*)&Ks[swz(wc * 32 + n * 16 + lr, eo)];
#pragma unroll
        for (int m = 0; m < 2; ++m)
#pragma unroll
            for (int n = 0; n < 2; ++n)
                accp[m][n] = __builtin_amdgcn_mfma_f32_16x16x32_bf16(a[m], bfr[n], accp[m][n], 0, 0, 0);
    }
#pragma unroll
    for (int m = 0; m < 2; ++m)
#pragma unroll
        for (int n = 0; n < 2; ++n)
#pragma unroll
            for (int j = 0; j < 4; ++j) {
                int t = wr * 32 + m * 16 + lk * 4 + j;
                int s = wc * 32 + n * 16 + lr;
                int dt = t - s;
                float v = (dt >= 0) ? accp[m][n][j] * exp2f((float)dt * l2g) : 0.0f;
                Ps[swz(t, s)] = f2bf(v);
            }
    __syncthreads();

    // phase B
    f32x4 accy[2][2], accz[2][2];
#pragma unroll
    for (int m = 0; m < 2; ++m)
#pragma unroll
        for (int n = 0; n < 2; ++n) {
            accy[m][n] = (f32x4){0.f, 0.f, 0.f, 0.f};
            accz[m][n] = (f32x4){0.f, 0.f, 0.f, 0.f};
        }
#pragma unroll
    for (int kk = 0; kk < 2; ++kk) {
        const int so = kk * 32 + lk * 8;
        bf16x8 pa[2], qa[2], vb[2], sb[2];
#pragma unroll
        for (int m = 0; m < 2; ++m) {
            pa[m] = *(const bf16x8*)&Ps[swz(wr * 32 + m * 16 + lr, so)];
            qa[m] = *(const bf16x8*)&Qs[swz(wr * 32 + m * 16 + lr, so)];
        }
#pragma unroll
        for (int n = 0; n < 2; ++n) {
            vb[n] = *(const bf16x8*)&Vt[swz(wc * 32 + n * 16 + lr, so)];
            sb[n] = *(const bf16x8*)&Ss[swz(wc * 32 + n * 16 + lr, so)];
        }
#pragma unroll
        for (int m = 0; m < 2; ++m)
#pragma unroll
            for (int n = 0; n < 2; ++n) {
                accy[m][n] = __builtin_amdgcn_mfma_f32_16x16x32_bf16(pa[m], vb[n], accy[m][n], 0, 0, 0);
                accz[m][n] = __builtin_amdgcn_mfma_f32_16x16x32_bf16(qa[m], sb[n], accz[m][n], 0, 0, 0);
            }
    }
    __syncthreads();   // Ps reads done; safe to overwrite as Y-staging

#pragma unroll
    for (int m = 0; m < 2; ++m)
#pragma unroll
        for (int n = 0; n < 2; ++n)
#pragma unroll
            for (int j = 0; j < 4; ++j) {
                int t = wr * 32 + m * 16 + lk * 4 + j;
                int d = wc * 32 + n * 16 + lr;
                float g = exp2f((float)(t + 1) * l2g);
                Ps[swz(t, d)] = f2bf(accy[m][n][j] + g * accz[m][n][j]);
            }
    __syncthreads();

    // coalesced write: each row = 128B contiguous
#pragma unroll
    for (int i = 0; i < 2; ++i) {
        int f  = tid + i * 256;
        int rr = f >> 3;
        int ch = f & 7;
        bf16x8 val = *(const bf16x8*)&Ps[swz(rr, ch * 8)];
        unsigned short* p = Y + ((size_t)(b * NL + c * CK + rr)) * ND + h * DKH + ch * 8;
        *(bf16x8*)p = val;
    }
}

extern "C" void kernel_launch(void* const* d_in, const int* in_sizes, int n_in,
                              void* d_out, int out_size, void* d_ws, size_t ws_size,
                              hipStream_t stream)
{
    (void)in_sizes; (void)n_in; (void)out_size; (void)ws_size;
    const float* x  = (const float*)d_in[0];
    const float* Wq = (const float*)d_in[1];
    const float* Wo = (const float*)d_in[2];
    const float* lg = (const float*)d_in[3];
    float* out = (float*)d_out;

    const size_t SZ = (size_t)NB * NH * NL * DKH;
    unsigned short* xb  = (unsigned short*)d_ws;
    unsigned short* Wqb = xb + SZ;
    unsigned short* Wob = Wqb + (size_t)3 * ND * ND;
    unsigned short* Qb  = Wob + (size_t)ND * ND;
    unsigned short* Kb  = Qb + SZ;
    unsigned short* Vb  = Kb + SZ;
    unsigned short* SL  = Vb + SZ;
    unsigned short* SS  = SL + SZ;
    unsigned short* Ybb = SS + SZ;

    k_cast_all<<<2048, 256, 0, stream>>>(x, Wq, Wo, xb, Wqb, Wob);
    k_gemm_qkv_bf16<<<dim3(3 * ND / 128, NM / 128), 256, 0, stream>>>(xb, Wqb, Qb, Kb, Vb);
    k_chunk_state<<<dim3(NB * NH * NCH), 256, 0, stream>>>(Kb, Vb, lg, SL);
    k_scan<<<dim3(NB * NH, 4), 256, 0, stream>>>(SL, lg, SS);
    k_chunk_out<<<dim3(NB * NH * NCH), 256, 0, stream>>>(Qb, Kb, Vb, SS, lg, Ybb);
    k_gemm_out_bf16<<<dim3(ND / 128, NM / 128), 256, 0, stream>>>(Ybb, Wob, out);
}